// Round 6
// baseline (68.885 us; speedup 1.0000x reference)
//
#include <hip/hip_runtime.h>
#include <hip/hip_bf16.h>

#define NB 64
#define NN 512
#define CI 32
#define CO 64
#define XN 68
#define YR 80   // Yext rows per batch: 64 Y + mc + dg + 14 pad

typedef __attribute__((ext_vector_type(8))) short bf16x8;
typedef __attribute__((ext_vector_type(4))) float f32x4;

__device__ inline short f2bf(float f) {
  union { __hip_bfloat16 h; unsigned short u; } cv;
  cv.h = __float2bfloat16(f);
  return (short)cv.u;
}

__device__ inline bf16x8 cvt8(float4 a, float4 b) {
  bf16x8 r;
  r[0] = f2bf(a.x); r[1] = f2bf(a.y); r[2] = f2bf(a.z); r[3] = f2bf(a.w);
  r[4] = f2bf(b.x); r[5] = f2bf(b.y); r[6] = f2bf(b.z); r[7] = f2bf(b.w);
  return r;
}

__device__ inline bf16x8 cvt8s(float4 a, float4 b, float s) {
  bf16x8 r;
  r[0] = f2bf(a.x * s); r[1] = f2bf(a.y * s); r[2] = f2bf(a.z * s); r[3] = f2bf(a.w * s);
  r[4] = f2bf(b.x * s); r[5] = f2bf(b.y * s); r[6] = f2bf(b.z * s); r[7] = f2bf(b.w * s);
  return r;
}

// ---------------- K1: A row stats. grid (NB, 32), 16 rows/block ----------------
__global__ __launch_bounds__(256) void k1_rowstats(
    const float* __restrict__ A, float* __restrict__ mc, float* __restrict__ dg,
    float* __restrict__ pA, float* __restrict__ pD) {
  int b = blockIdx.x, ch = blockIdx.y;
  int t = threadIdx.x, w = t >> 6, lane = t & 63;
  int r0 = ch * 16;
  const float* Ab = A + (size_t)b * NN * NN;
  __shared__ float wsum[4];
  __shared__ float sD[16];
  float4 v0[4], v1[4];
#pragma unroll
  for (int m = 0; m < 4; ++m) {
    const float* rp = Ab + (size_t)(r0 + w * 4 + m) * NN;
    v0[m] = *(const float4*)(rp + lane * 4);
    v1[m] = *(const float4*)(rp + 256 + lane * 4);
  }
  float accR = 0.f;
#pragma unroll
  for (int m = 0; m < 4; ++m) {
    float s = (v0[m].x + v0[m].y) + (v0[m].z + v0[m].w) +
              (v1[m].x + v1[m].y) + (v1[m].z + v1[m].w);
#pragma unroll
    for (int off = 1; off < 64; off <<= 1) s += __shfl_xor(s, off, 64);
    if (lane == 0) mc[b * NN + r0 + w * 4 + m] = s * (1.0f / NN);
    accR += s;
  }
  if (lane == 0) wsum[w] = accR;
  if (t < 16) {
    float d = Ab[(size_t)(r0 + t) * NN + r0 + t];
    dg[b * NN + r0 + t] = d;
    sD[t] = d;
  }
  __syncthreads();
  if (t == 0) {
    pA[b * 32 + ch] = wsum[0] + wsum[1] + wsum[2] + wsum[3];
    float sd = 0.f;
#pragma unroll
    for (int k = 0; k < 16; ++k) sd += sD[k];
    pD[b * 32 + ch] = sd;
  }
}

// ---------------- KY: Y = X @ W1c^T (bf16), no stats deps. grid (NB, 4) ----------------
__global__ __launch_bounds__(256) void kY(
    const float* __restrict__ X, const float* __restrict__ W1,
    unsigned short* __restrict__ Yext) {
  int b = blockIdx.x, yc = blockIdx.y;
  int t = threadIdx.x, w = t >> 6, lane = t & 63;
  int ra = lane & 15, kg = lane >> 4, g = lane >> 4;
  const float* Xb = X + (size_t)b * NN * CI;

  bf16x8 wfrag[4];
#pragma unroll
  for (int to = 0; to < 4; ++to) {
    const float* wp = W1 + (to * 16 + ra) * XN + kg * 8;
    wfrag[to] = cvt8(*(const float4*)wp, *(const float4*)(wp + 4));
  }
#pragma unroll
  for (int jj = 0; jj < 2; ++jj) {
    int j0 = yc * 128 + w * 32 + jj * 16;
    const float* xp = Xb + (size_t)(j0 + ra) * CI + kg * 8;
    bf16x8 xf = cvt8(*(const float4*)xp, *(const float4*)(xp + 4));
#pragma unroll
    for (int to = 0; to < 4; ++to) {
      f32x4 zero = {0.f, 0.f, 0.f, 0.f};
      f32x4 d = __builtin_amdgcn_mfma_f32_16x16x32_bf16(xf, wfrag[to], zero, 0, 0, 0);
      union { unsigned short u[4]; uint2 v; } pk;
#pragma unroll
      for (int r = 0; r < 4; ++r) pk.u[r] = (unsigned short)f2bf(d[r]);
      *(uint2*)(Yext + ((size_t)b * YR + to * 16 + ra) * NN + j0 + g * 4) = pk.v;
    }
  }
  // zero pad rows 66..79 for this j-range (defensive vs poisoned ws)
  for (int idx = t; idx < 14 * 32; idx += 256) {
    int row = 66 + (idx >> 5);
    int c4 = (idx & 31) * 4;
    *(uint2*)(Yext + ((size_t)b * YR + row) * NN + yc * 128 + c4) = make_uint2(0u, 0u);
  }
}

// ---------------- K2: per-batch stats + colv + vplus + Yext rows 64/65. grid (NB) ----------------
__global__ __launch_bounds__(1024) void k2_stats(
    const float* __restrict__ X, const float* __restrict__ cf,
    const float* __restrict__ W1, const float* __restrict__ W2,
    const float* __restrict__ mc, const float* __restrict__ dg,
    const float* __restrict__ pA, const float* __restrict__ pD,
    float* __restrict__ vplus, float* __restrict__ colv,
    unsigned short* __restrict__ Yext) {
  int b = blockIdx.x, t = threadIdx.x;
  int w = t >> 6, lane = t & 63;
  int h = t & 1, j = t >> 1;
  __shared__ float sMXp[16][32], sTCp[16][32], sP[16][3];
  __shared__ float sc[69], mX[CI], tC[CI];
  __shared__ float sS[6];  // 0:md 1:ma 2:scst 3:ssum 4:ssmc 5:ssdg

  if (t < 69) sc[t] = cf[t];
  const float* xp = X + ((size_t)b * NN + j) * CI + h * 16;
  float4 x4[4];
#pragma unroll
  for (int k = 0; k < 4; ++k) x4[k] = *(const float4*)(xp + k * 4);
  float mcj = mc[b * NN + j], dgj = dg[b * NN + j];
  __syncthreads();  // sc ready

  float up = 0.f;
#pragma unroll
  for (int k = 0; k < 4; ++k) {
    int c0 = 5 + h * 16 + k * 4;
    up += sc[c0] * x4[k].x + sc[c0 + 1] * x4[k].y +
          sc[c0 + 2] * x4[k].z + sc[c0 + 3] * x4[k].w;
  }
  float u = up + __shfl_xor(up, 1, 64);
  float vec = fmaf(sc[3], mcj, fmaf(sc[4], dgj, u));

  float p1 = h ? 0.f : vec;
  float p2 = h ? 0.f : vec * mcj;
  float p3 = h ? 0.f : vec * dgj;
  float4 t4[4];
#pragma unroll
  for (int k = 0; k < 4; ++k) {
    t4[k].x = vec * x4[k].x; t4[k].y = vec * x4[k].y;
    t4[k].z = vec * x4[k].z; t4[k].w = vec * x4[k].w;
  }
#pragma unroll
  for (int off = 1; off < 64; off <<= 1) {
    p1 += __shfl_xor(p1, off, 64);
    p2 += __shfl_xor(p2, off, 64);
    p3 += __shfl_xor(p3, off, 64);
  }
#pragma unroll
  for (int off = 2; off < 64; off <<= 1) {
#pragma unroll
    for (int k = 0; k < 4; ++k) {
      x4[k].x += __shfl_xor(x4[k].x, off, 64);
      x4[k].y += __shfl_xor(x4[k].y, off, 64);
      x4[k].z += __shfl_xor(x4[k].z, off, 64);
      x4[k].w += __shfl_xor(x4[k].w, off, 64);
      t4[k].x += __shfl_xor(t4[k].x, off, 64);
      t4[k].y += __shfl_xor(t4[k].y, off, 64);
      t4[k].z += __shfl_xor(t4[k].z, off, 64);
      t4[k].w += __shfl_xor(t4[k].w, off, 64);
    }
  }
  if (lane < 2) {
#pragma unroll
    for (int k = 0; k < 4; ++k) {
      *(float4*)&sMXp[w][lane * 16 + k * 4] = x4[k];
      *(float4*)&sTCp[w][lane * 16 + k * 4] = t4[k];
    }
    if (lane == 0) { sP[w][0] = p1; sP[w][1] = p2; sP[w][2] = p3; }
  }
  __syncthreads();
  if (t < 32) {
    float s1 = 0.f, s2 = 0.f;
#pragma unroll
    for (int g = 0; g < 16; ++g) { s1 += sMXp[g][t]; s2 += sTCp[g][t]; }
    mX[t] = s1 * (1.0f / NN);
    tC[t] = s2;
  } else if (t == 32) {
    float sA = 0.f, sD = 0.f;
#pragma unroll
    for (int k = 0; k < 32; ++k) { sA += pA[b * 32 + k]; sD += pD[b * 32 + k]; }
    sS[0] = sD * (1.0f / NN);
    sS[1] = sA * (1.0f / ((float)NN * (float)NN));
  } else if (t == 33) {
    float s1 = 0.f, s2 = 0.f, s3 = 0.f;
#pragma unroll
    for (int k = 0; k < 16; ++k) { s1 += sP[k][0]; s2 += sP[k][1]; s3 += sP[k][2]; }
    sS[3] = s1; sS[4] = s2; sS[5] = s3;
  }
  __syncthreads();
  if (t == 0) {
    float s7 = 0.f;
#pragma unroll
    for (int c = 0; c < CI; ++c) s7 += sc[5 + CI + c] * mX[c];
    sS[2] = sc[1] * sS[1] + sc[2] * sS[0] + s7;
  }
  __syncthreads();
  if (h == 0) vplus[b * NN + j] = vec + sS[2];
  // Yext rows 64 (mc) and 65 (dg), bf16
  if (t < NN) {
    Yext[((size_t)b * YR + 64) * NN + t] = (unsigned short)f2bf(mc[b * NN + t]);
  } else {
    int t2 = t - NN;
    Yext[((size_t)b * YR + 65) * NN + t2] = (unsigned short)f2bf(dg[b * NN + t2]);
  }
  if (t < CO) {
    int o = t;
    const float* w1 = W1 + o * XN;
    const float* w2 = W2 + o * XN;
    float w1mX = 0.f, a1 = 0.f, a2 = 0.f, wt = 0.f;
#pragma unroll
    for (int c = 0; c < CI; ++c) {
      w1mX += w1[c] * mX[c];
      a1 += w1[CI + c] * mX[c];
      a2 += w2[CI + c] * mX[c];
      wt += w1[c] * tC[c];
    }
    float smd = sS[0], sma = sS[1];
    a1 += w1[66] * smd + w1[67] * sma;
    a2 += w2[66] * smd + w2[67] * sma;
    float we0 = w1[64], we1 = w1[65];
    float S1n = w1mX + a1 + we0 * sma + we1 * smd;
    float SVn = (wt + a1 * sS[3] + we0 * sS[4] + we1 * sS[5]) * (1.0f / NN);
    float4 cva = make_float4(S1n, a2 + SVn, w2[64] + sc[0] * a1, w2[65]);
    float4 cvb = make_float4(we0, we1, 0.f, 0.f);
    *(float4*)&colv[(b * CO + o) * 8] = cva;
    *(float4*)&colv[(b * CO + o) * 8 + 4] = cvb;
  }
}

// ---------------- K5: batched MFMA GEMM + Gmc/Gdg fragment + fused epilogue ----------------
__global__ __launch_bounds__(512) void k5_mfma(
    const float* __restrict__ A, const unsigned short* __restrict__ Yext,
    const float* __restrict__ X, const float* __restrict__ W2,
    const float* __restrict__ vplus, const float* __restrict__ mc,
    const float* __restrict__ dg, const float* __restrict__ colv,
    const float* __restrict__ cf, float* __restrict__ out) {
  int b = blockIdx.x, ic = blockIdx.y;
  int t = threadIdx.x, w = t >> 6, lane = t & 63;
  int ia = w & 1, q = w >> 1;
  int ra = lane & 15, kg = lane >> 4, g = lane >> 4;
  int i0 = ic * 32;
  __shared__ float sAcc[4 * 32 * 68];
  __shared__ float sG[4 * 32 * 2];

  float c0n = cf[0] * (1.0f / NN);
  const float* Arow = A + ((size_t)(b * NN + i0 + ia * 16 + ra)) * NN;
  const unsigned short* Yb = Yext + (size_t)b * YR * NN;

  f32x4 acc[4] = {{0.f, 0.f, 0.f, 0.f}, {0.f, 0.f, 0.f, 0.f},
                  {0.f, 0.f, 0.f, 0.f}, {0.f, 0.f, 0.f, 0.f}};
  f32x4 acc4 = {0.f, 0.f, 0.f, 0.f};

#pragma unroll
  for (int jt = 0; jt < 4; ++jt) {
    int kb = q * 128 + jt * 32 + kg * 8;
    float4 a0 = *(const float4*)(Arow + kb);
    float4 a1 = *(const float4*)(Arow + kb + 4);
    bf16x8 af = cvt8s(a0, a1, c0n);
#pragma unroll
    for (int to = 0; to < 4; ++to) {
      bf16x8 bf = *(const bf16x8*)(Yb + (size_t)(to * 16 + ra) * NN + kb);
      acc[to] = __builtin_amdgcn_mfma_f32_16x16x32_bf16(af, bf, acc[to], 0, 0, 0);
    }
    bf16x8 bf4 = *(const bf16x8*)(Yb + (size_t)(64 + ra) * NN + kb);
    acc4 = __builtin_amdgcn_mfma_f32_16x16x32_bf16(af, bf4, acc4, 0, 0, 0);
  }

  if (q == 0) {  // fused X*W2c k-step (unscaled)
    const float* xp = X + (size_t)(b * NN + i0 + ia * 16 + ra) * CI + kg * 8;
    bf16x8 xf = cvt8(*(const float4*)xp, *(const float4*)(xp + 4));
#pragma unroll
    for (int to = 0; to < 4; ++to) {
      const float* wp = W2 + (size_t)(to * 16 + ra) * XN + kg * 8;
      bf16x8 wf = cvt8(*(const float4*)wp, *(const float4*)(wp + 4));
      acc[to] = __builtin_amdgcn_mfma_f32_16x16x32_bf16(xf, wf, acc[to], 0, 0, 0);
    }
  }

  // epilogue prefetch before LDS store + barrier
  int ei = t >> 4, eo4 = (t & 15) * 4;
  float e_vp = vplus[b * NN + i0 + ei];
  float e_mc = mc[b * NN + i0 + ei];
  float e_dg = dg[b * NN + i0 + ei];
  float4 cva0 = *(const float4*)&colv[(b * CO + eo4 + 0) * 8];
  float4 cvb0 = *(const float4*)&colv[(b * CO + eo4 + 0) * 8 + 4];
  float4 cva1 = *(const float4*)&colv[(b * CO + eo4 + 1) * 8];
  float4 cvb1 = *(const float4*)&colv[(b * CO + eo4 + 1) * 8 + 4];
  float4 cva2 = *(const float4*)&colv[(b * CO + eo4 + 2) * 8];
  float4 cvb2 = *(const float4*)&colv[(b * CO + eo4 + 2) * 8 + 4];
  float4 cva3 = *(const float4*)&colv[(b * CO + eo4 + 3) * 8];
  float4 cvb3 = *(const float4*)&colv[(b * CO + eo4 + 3) * 8 + 4];

#pragma unroll
  for (int to = 0; to < 4; ++to)
#pragma unroll
    for (int r = 0; r < 4; ++r)
      sAcc[(q * 32 + ia * 16 + g * 4 + r) * 68 + to * 16 + ra] = acc[to][r];
  if (ra < 2) {
#pragma unroll
    for (int r = 0; r < 4; ++r)
      sG[((q * 32 + ia * 16 + g * 4 + r) << 1) | ra] = acc4[r];
  }
  __syncthreads();

  {
    f32x4 s = {0.f, 0.f, 0.f, 0.f};
    float Gm = 0.f, Gd = 0.f;
#pragma unroll
    for (int qq = 0; qq < 4; ++qq) {
      s += *(const f32x4*)&sAcc[(qq * 32 + ei) * 68 + eo4];
      Gm += sG[((qq * 32 + ei) << 1)];
      Gd += sG[((qq * 32 + ei) << 1) | 1];
    }
    float4 res;
    res.x = s[0] + e_vp * cva0.x + cva0.y + e_mc * cva0.z + e_dg * cva0.w + Gm * cvb0.x + Gd * cvb0.y;
    res.y = s[1] + e_vp * cva1.x + cva1.y + e_mc * cva1.z + e_dg * cva1.w + Gm * cvb1.x + Gd * cvb1.y;
    res.z = s[2] + e_vp * cva2.x + cva2.y + e_mc * cva2.z + e_dg * cva2.w + Gm * cvb2.x + Gd * cvb2.y;
    res.w = s[3] + e_vp * cva3.x + cva3.y + e_mc * cva3.z + e_dg * cva3.w + Gm * cvb3.x + Gd * cvb3.y;
    *(float4*)&out[((size_t)(b * NN + i0 + ei)) * CO + eo4] = res;
  }
}

extern "C" void kernel_launch(void* const* d_in, const int* in_sizes, int n_in,
                              void* d_out, int out_size, void* d_ws, size_t ws_size,
                              hipStream_t stream) {
  const float* A = (const float*)d_in[0];
  const float* X = (const float*)d_in[1];
  const float* cf = (const float*)d_in[2];
  const float* W1 = (const float*)d_in[3];
  const float* W2 = (const float*)d_in[4];
  float* out = (float*)d_out;

  float* p = (float*)d_ws;
  float* mc = p;      p += NB * NN;
  float* dg = p;      p += NB * NN;
  float* vplus = p;   p += NB * NN;
  float* pA = p;      p += NB * 32;
  float* pD = p;      p += NB * 32;
  float* colv = p;    p += NB * CO * 8;
  unsigned short* Yext = (unsigned short*)p;

  k1_rowstats<<<dim3(NB, 32), 256, 0, stream>>>(A, mc, dg, pA, pD);
  kY<<<dim3(NB, 4), 256, 0, stream>>>(X, W1, Yext);
  k2_stats<<<NB, 1024, 0, stream>>>(X, cf, W1, W2, mc, dg, pA, pD,
                                    vplus, colv, Yext);
  k5_mfma<<<dim3(NB, 16), 512, 0, stream>>>(A, Yext, X, W2, vplus, mc, dg,
                                            colv, cf, out);
}

// Round 7
// 63.722 us; speedup vs baseline: 1.0810x; 1.0810x over previous
//
#include <hip/hip_runtime.h>
#include <hip/hip_bf16.h>

#define NB 64
#define NN 512
#define CI 32
#define CO 64
#define XN 68
#define YR 80   // Yext rows per batch: 64 Y + mc + dg + 14 pad

typedef __attribute__((ext_vector_type(8))) short bf16x8;
typedef __attribute__((ext_vector_type(4))) float f32x4;

__device__ inline short f2bf(float f) {
  union { __hip_bfloat16 h; unsigned short u; } cv;
  cv.h = __float2bfloat16(f);
  return (short)cv.u;
}

__device__ inline bf16x8 cvt8(float4 a, float4 b) {
  bf16x8 r;
  r[0] = f2bf(a.x); r[1] = f2bf(a.y); r[2] = f2bf(a.z); r[3] = f2bf(a.w);
  r[4] = f2bf(b.x); r[5] = f2bf(b.y); r[6] = f2bf(b.z); r[7] = f2bf(b.w);
  return r;
}

__device__ inline bf16x8 cvt8s(float4 a, float4 b, float s) {
  bf16x8 r;
  r[0] = f2bf(a.x * s); r[1] = f2bf(a.y * s); r[2] = f2bf(a.z * s); r[3] = f2bf(a.w * s);
  r[4] = f2bf(b.x * s); r[5] = f2bf(b.y * s); r[6] = f2bf(b.z * s); r[7] = f2bf(b.w * s);
  return r;
}

// ---------------- K1X: A row stats + X chunk stats. grid (NB, 32), 16 rows/block ----------------
__global__ __launch_bounds__(256) void k1x(
    const float* __restrict__ A, const float* __restrict__ X,
    const float* __restrict__ cf,
    float* __restrict__ mc, float* __restrict__ dg, float* __restrict__ vec,
    float* __restrict__ pA, float* __restrict__ pD,
    float* __restrict__ pmX, float* __restrict__ ptC, float* __restrict__ pS) {
  int b = blockIdx.x, ch = blockIdx.y;
  int t = threadIdx.x, w = t >> 6, lane = t & 63;
  int r0 = ch * 16;
  const float* Ab = A + (size_t)b * NN * NN;
  __shared__ float wsum[4], sDg[16], sMc[16], sVec[16];
  __shared__ float sXc[16][33];
  __shared__ float scf[69];
  if (t < 69) scf[t] = cf[t];
  // stage X chunk: 16 rows x 32 cols
  {
    int j = t >> 4, c = (t & 15) * 2;
    float2 xv = *(const float2*)(X + ((size_t)b * NN + r0 + j) * CI + c);
    sXc[j][c] = xv.x; sXc[j][c + 1] = xv.y;
  }
  float4 v0[4], v1[4];
#pragma unroll
  for (int m = 0; m < 4; ++m) {
    const float* rp = Ab + (size_t)(r0 + w * 4 + m) * NN;
    v0[m] = *(const float4*)(rp + lane * 4);
    v1[m] = *(const float4*)(rp + 256 + lane * 4);
  }
  float accR = 0.f;
#pragma unroll
  for (int m = 0; m < 4; ++m) {
    float s = (v0[m].x + v0[m].y) + (v0[m].z + v0[m].w) +
              (v1[m].x + v1[m].y) + (v1[m].z + v1[m].w);
#pragma unroll
    for (int off = 1; off < 64; off <<= 1) s += __shfl_xor(s, off, 64);
    if (lane == 0) {
      float m_ = s * (1.0f / NN);
      mc[b * NN + r0 + w * 4 + m] = m_;
      sMc[w * 4 + m] = m_;
    }
    accR += s;
  }
  if (lane == 0) wsum[w] = accR;
  if (t < 16) {
    float d = Ab[(size_t)(r0 + t) * NN + r0 + t];
    dg[b * NN + r0 + t] = d;
    sDg[t] = d;
  }
  __syncthreads();
  if (t < 16) {
    float u = 0.f;
#pragma unroll
    for (int c = 0; c < CI; ++c) u += scf[5 + c] * sXc[t][c];
    float vj = scf[3] * sMc[t] + scf[4] * sDg[t] + u;
    vec[b * NN + r0 + t] = vj;
    sVec[t] = vj;
  } else if (t == 16) {
    pA[b * 32 + ch] = wsum[0] + wsum[1] + wsum[2] + wsum[3];
    float sd = 0.f;
#pragma unroll
    for (int k = 0; k < 16; ++k) sd += sDg[k];
    pD[b * 32 + ch] = sd;
  }
  __syncthreads();
  if (t < 32) {
    float s1 = 0.f, s2 = 0.f;
#pragma unroll
    for (int r = 0; r < 16; ++r) {
      float xv = sXc[r][t];
      s1 += xv;
      s2 += sVec[r] * xv;
    }
    pmX[((size_t)b * 32 + ch) * 32 + t] = s1;
    ptC[((size_t)b * 32 + ch) * 32 + t] = s2;
  } else if (t < 35) {
    float s = 0.f;
    if (t == 32) { for (int r = 0; r < 16; ++r) s += sVec[r]; }
    if (t == 33) { for (int r = 0; r < 16; ++r) s += sVec[r] * sMc[r]; }
    if (t == 34) { for (int r = 0; r < 16; ++r) s += sVec[r] * sDg[r]; }
    pS[((size_t)b * 32 + ch) * 3 + (t - 32)] = s;
  }
}

// ---------------- KY: Yext = [X@W1c^T; mc; dg; 0pad] (bf16). grid (NB, 4) ----------------
__global__ __launch_bounds__(256) void kY(
    const float* __restrict__ X, const float* __restrict__ W1,
    const float* __restrict__ mc, const float* __restrict__ dg,
    unsigned short* __restrict__ Yext) {
  int b = blockIdx.x, yc = blockIdx.y;
  int t = threadIdx.x, w = t >> 6, lane = t & 63;
  int ra = lane & 15, kg = lane >> 4, g = lane >> 4;
  const float* Xb = X + (size_t)b * NN * CI;

  bf16x8 wfrag[4];
#pragma unroll
  for (int to = 0; to < 4; ++to) {
    const float* wp = W1 + (to * 16 + ra) * XN + kg * 8;
    wfrag[to] = cvt8(*(const float4*)wp, *(const float4*)(wp + 4));
  }
#pragma unroll
  for (int jj = 0; jj < 2; ++jj) {
    int j0 = yc * 128 + w * 32 + jj * 16;
    const float* xp = Xb + (size_t)(j0 + ra) * CI + kg * 8;
    bf16x8 xf = cvt8(*(const float4*)xp, *(const float4*)(xp + 4));
#pragma unroll
    for (int to = 0; to < 4; ++to) {
      f32x4 zero = {0.f, 0.f, 0.f, 0.f};
      f32x4 d = __builtin_amdgcn_mfma_f32_16x16x32_bf16(xf, wfrag[to], zero, 0, 0, 0);
      union { unsigned short u[4]; uint2 v; } pk;
#pragma unroll
      for (int r = 0; r < 4; ++r) pk.u[r] = (unsigned short)f2bf(d[r]);
      *(uint2*)(Yext + ((size_t)b * YR + to * 16 + ra) * NN + j0 + g * 4) = pk.v;
    }
  }
  // rows 64 (mc), 65 (dg) for this column range
  if (t < 128) {
    int col = yc * 128 + t;
    Yext[((size_t)b * YR + 64) * NN + col] = (unsigned short)f2bf(mc[b * NN + col]);
  } else {
    int col = yc * 128 + (t - 128);
    Yext[((size_t)b * YR + 65) * NN + col] = (unsigned short)f2bf(dg[b * NN + col]);
  }
  // zero pad rows 66..79 for this column range
  for (int idx = t; idx < 14 * 32; idx += 256) {
    int row = 66 + (idx >> 5);
    int c4 = (idx & 31) * 4;
    *(uint2*)(Yext + ((size_t)b * YR + row) * NN + yc * 128 + c4) = make_uint2(0u, 0u);
  }
}

// ---------------- KW: finalize stats -> colv, sconst. grid (16) ----------------
__global__ __launch_bounds__(256) void kW(
    const float* __restrict__ cf, const float* __restrict__ W1,
    const float* __restrict__ W2, const float* __restrict__ pA,
    const float* __restrict__ pD, const float* __restrict__ pmX,
    const float* __restrict__ ptC, const float* __restrict__ pS,
    float* __restrict__ colv, float* __restrict__ sconst) {
  int gb = blockIdx.x, t = threadIdx.x;
  int bb0 = gb * 4;
  __shared__ float sW1[64][69], sW2[64][69];
  __shared__ float mXs[4][33], tCs[4][33];
  __shared__ float scal[4][6];  // 0:md 1:ma 2:ssum 3:ssmc 4:ssdg 5:scst
  __shared__ float scf[69];
  if (t < 69) scf[t] = cf[t];
  for (int idx = t; idx < 64 * XN; idx += 256) {
    int r = idx / XN, c = idx - r * XN;
    sW1[r][c] = W1[idx];
    sW2[r][c] = W2[idx];
  }
  if (t < 128) {
    int bb = t >> 5, c = t & 31, b = bb0 + bb;
    float s1 = 0.f, s2 = 0.f;
#pragma unroll
    for (int k = 0; k < 32; ++k) {
      s1 += pmX[((size_t)b * 32 + k) * 32 + c];
      s2 += ptC[((size_t)b * 32 + k) * 32 + c];
    }
    mXs[bb][c] = s1 * (1.0f / NN);
    tCs[bb][c] = s2;
  } else if (t < 132) {
    int bb = t - 128, b = bb0 + bb;
    float sA = 0.f, sD = 0.f;
#pragma unroll
    for (int k = 0; k < 32; ++k) { sA += pA[b * 32 + k]; sD += pD[b * 32 + k]; }
    scal[bb][0] = sD * (1.0f / NN);
    scal[bb][1] = sA * (1.0f / ((float)NN * (float)NN));
  } else if (t < 136) {
    int bb = t - 132, b = bb0 + bb;
    float s1 = 0.f, s2 = 0.f, s3 = 0.f;
#pragma unroll
    for (int k = 0; k < 32; ++k) {
      s1 += pS[((size_t)b * 32 + k) * 3 + 0];
      s2 += pS[((size_t)b * 32 + k) * 3 + 1];
      s3 += pS[((size_t)b * 32 + k) * 3 + 2];
    }
    scal[bb][2] = s1; scal[bb][3] = s2; scal[bb][4] = s3;
  }
  __syncthreads();
  if (t < 4) {
    float s7 = 0.f;
#pragma unroll
    for (int c = 0; c < CI; ++c) s7 += scf[5 + CI + c] * mXs[t][c];
    float scst = scf[1] * scal[t][1] + scf[2] * scal[t][0] + s7;
    sconst[bb0 + t] = scst;
  }
  {
    int bb = t >> 6, o = t & 63, b = bb0 + bb;
    float w1mX = 0.f, a1 = 0.f, a2 = 0.f, wt = 0.f;
#pragma unroll
    for (int c = 0; c < CI; ++c) {
      float m = mXs[bb][c];
      w1mX += sW1[o][c] * m;
      a1 += sW1[o][CI + c] * m;
      a2 += sW2[o][CI + c] * m;
      wt += sW1[o][c] * tCs[bb][c];
    }
    float smd = scal[bb][0], sma = scal[bb][1];
    a1 += sW1[o][66] * smd + sW1[o][67] * sma;
    a2 += sW2[o][66] * smd + sW2[o][67] * sma;
    float we0 = sW1[o][64], we1 = sW1[o][65];
    float S1n = w1mX + a1 + we0 * sma + we1 * smd;
    float SVn = (wt + a1 * scal[bb][2] + we0 * scal[bb][3] + we1 * scal[bb][4]) * (1.0f / NN);
    float4 cva = make_float4(S1n, a2 + SVn, sW2[o][64] + scf[0] * a1, sW2[o][65]);
    float4 cvb = make_float4(we0, we1, 0.f, 0.f);
    *(float4*)&colv[((size_t)b * CO + o) * 8] = cva;
    *(float4*)&colv[((size_t)b * CO + o) * 8 + 4] = cvb;
  }
}

// ---------------- K5: batched MFMA GEMM + Gmc/Gdg fragment + fused epilogue ----------------
__global__ __launch_bounds__(512) void k5_mfma(
    const float* __restrict__ A, const unsigned short* __restrict__ Yext,
    const float* __restrict__ X, const float* __restrict__ W2,
    const float* __restrict__ vec, const float* __restrict__ mc,
    const float* __restrict__ dg, const float* __restrict__ colv,
    const float* __restrict__ sconst, const float* __restrict__ cf,
    float* __restrict__ out) {
  int b = blockIdx.x, ic = blockIdx.y;
  int t = threadIdx.x, w = t >> 6, lane = t & 63;
  int ia = w & 1, q = w >> 1;
  int ra = lane & 15, kg = lane >> 4, g = lane >> 4;
  int i0 = ic * 32;
  __shared__ float sAcc[4 * 32 * 68];
  __shared__ float sG[4 * 32 * 2];

  float c0n = cf[0] * (1.0f / NN);
  const float* Arow = A + ((size_t)(b * NN + i0 + ia * 16 + ra)) * NN;
  const unsigned short* Yb = Yext + (size_t)b * YR * NN;

  f32x4 acc[4] = {{0.f, 0.f, 0.f, 0.f}, {0.f, 0.f, 0.f, 0.f},
                  {0.f, 0.f, 0.f, 0.f}, {0.f, 0.f, 0.f, 0.f}};
  f32x4 acc4 = {0.f, 0.f, 0.f, 0.f};

#pragma unroll
  for (int jt = 0; jt < 4; ++jt) {
    int kb = q * 128 + jt * 32 + kg * 8;
    float4 a0 = *(const float4*)(Arow + kb);
    float4 a1 = *(const float4*)(Arow + kb + 4);
    bf16x8 af = cvt8s(a0, a1, c0n);
#pragma unroll
    for (int to = 0; to < 4; ++to) {
      bf16x8 bf = *(const bf16x8*)(Yb + (size_t)(to * 16 + ra) * NN + kb);
      acc[to] = __builtin_amdgcn_mfma_f32_16x16x32_bf16(af, bf, acc[to], 0, 0, 0);
    }
    bf16x8 bf4 = *(const bf16x8*)(Yb + (size_t)(64 + ra) * NN + kb);
    acc4 = __builtin_amdgcn_mfma_f32_16x16x32_bf16(af, bf4, acc4, 0, 0, 0);
  }

  if (q == 0) {  // fused X*W2c k-step (unscaled)
    const float* xp = X + (size_t)(b * NN + i0 + ia * 16 + ra) * CI + kg * 8;
    bf16x8 xf = cvt8(*(const float4*)xp, *(const float4*)(xp + 4));
#pragma unroll
    for (int to = 0; to < 4; ++to) {
      const float* wp = W2 + (size_t)(to * 16 + ra) * XN + kg * 8;
      bf16x8 wf = cvt8(*(const float4*)wp, *(const float4*)(wp + 4));
      acc[to] = __builtin_amdgcn_mfma_f32_16x16x32_bf16(xf, wf, acc[to], 0, 0, 0);
    }
  }

  // epilogue prefetch before LDS store + barrier
  int ei = t >> 4, eo4 = (t & 15) * 4;
  float e_vp = vec[b * NN + i0 + ei] + sconst[b];
  float e_mc = mc[b * NN + i0 + ei];
  float e_dg = dg[b * NN + i0 + ei];
  float4 cva0 = *(const float4*)&colv[((size_t)b * CO + eo4 + 0) * 8];
  float4 cvb0 = *(const float4*)&colv[((size_t)b * CO + eo4 + 0) * 8 + 4];
  float4 cva1 = *(const float4*)&colv[((size_t)b * CO + eo4 + 1) * 8];
  float4 cvb1 = *(const float4*)&colv[((size_t)b * CO + eo4 + 1) * 8 + 4];
  float4 cva2 = *(const float4*)&colv[((size_t)b * CO + eo4 + 2) * 8];
  float4 cvb2 = *(const float4*)&colv[((size_t)b * CO + eo4 + 2) * 8 + 4];
  float4 cva3 = *(const float4*)&colv[((size_t)b * CO + eo4 + 3) * 8];
  float4 cvb3 = *(const float4*)&colv[((size_t)b * CO + eo4 + 3) * 8 + 4];

#pragma unroll
  for (int to = 0; to < 4; ++to)
#pragma unroll
    for (int r = 0; r < 4; ++r)
      sAcc[(q * 32 + ia * 16 + g * 4 + r) * 68 + to * 16 + ra] = acc[to][r];
  if (ra < 2) {
#pragma unroll
    for (int r = 0; r < 4; ++r)
      sG[((q * 32 + ia * 16 + g * 4 + r) << 1) | ra] = acc4[r];
  }
  __syncthreads();

  {
    f32x4 s = {0.f, 0.f, 0.f, 0.f};
    float Gm = 0.f, Gd = 0.f;
#pragma unroll
    for (int qq = 0; qq < 4; ++qq) {
      s += *(const f32x4*)&sAcc[(qq * 32 + ei) * 68 + eo4];
      Gm += sG[((qq * 32 + ei) << 1)];
      Gd += sG[((qq * 32 + ei) << 1) | 1];
    }
    float4 res;
    res.x = s[0] + e_vp * cva0.x + cva0.y + e_mc * cva0.z + e_dg * cva0.w + Gm * cvb0.x + Gd * cvb0.y;
    res.y = s[1] + e_vp * cva1.x + cva1.y + e_mc * cva1.z + e_dg * cva1.w + Gm * cvb1.x + Gd * cvb1.y;
    res.z = s[2] + e_vp * cva2.x + cva2.y + e_mc * cva2.z + e_dg * cva2.w + Gm * cvb2.x + Gd * cvb2.y;
    res.w = s[3] + e_vp * cva3.x + cva3.y + e_mc * cva3.z + e_dg * cva3.w + Gm * cvb3.x + Gd * cvb3.y;
    *(float4*)&out[((size_t)(b * NN + i0 + ei)) * CO + eo4] = res;
  }
}

extern "C" void kernel_launch(void* const* d_in, const int* in_sizes, int n_in,
                              void* d_out, int out_size, void* d_ws, size_t ws_size,
                              hipStream_t stream) {
  const float* A = (const float*)d_in[0];
  const float* X = (const float*)d_in[1];
  const float* cf = (const float*)d_in[2];
  const float* W1 = (const float*)d_in[3];
  const float* W2 = (const float*)d_in[4];
  float* out = (float*)d_out;

  float* p = (float*)d_ws;
  float* mc = p;      p += NB * NN;
  float* dg = p;      p += NB * NN;
  float* vec = p;     p += NB * NN;
  float* pA = p;      p += NB * 32;
  float* pD = p;      p += NB * 32;
  float* pmX = p;     p += NB * 32 * 32;
  float* ptC = p;     p += NB * 32 * 32;
  float* pS = p;      p += NB * 32 * 3;
  float* colv = p;    p += NB * CO * 8;
  float* sconst = p;  p += NB;
  unsigned short* Yext = (unsigned short*)p;

  k1x<<<dim3(NB, 32), 256, 0, stream>>>(A, X, cf, mc, dg, vec, pA, pD, pmX, ptC, pS);
  kY<<<dim3(NB, 4), 256, 0, stream>>>(X, W1, mc, dg, Yext);
  kW<<<16, 256, 0, stream>>>(cf, W1, W2, pA, pD, pmX, ptC, pS, colv, sconst);
  k5_mfma<<<dim3(NB, 16), 512, 0, stream>>>(A, Yext, X, W2, vec, mc, dg,
                                            colv, sconst, cf, out);
}